// Round 17
// baseline (136.537 us; speedup 1.0000x reference)
//
#include <hip/hip_runtime.h>
#include <hip/hip_fp16.h>

constexpr int F_IN  = 9;
constexpr int F_HID = 32;
constexpr int F_OUT = 7;

constexpr int NBKT   = 586;      // ceil(150000/256) buckets of 256 nodes
constexpr int BCAP   = 4864;     // mean 4096 + 12 sigma
constexpr int CHUNK  = 4096;     // edges per scat block
constexpr int EPT    = CHUNK / 1024;   // 4 edges per thread in k_scat

__device__ __forceinline__ int nt_load_int(const int* p) {
    return __builtin_nontemporal_load(p);
}
__device__ __forceinline__ unsigned pack_h2(float a, float b) {
    return (unsigned)__half_as_ushort(__float2half(a)) |
           ((unsigned)__half_as_ushort(__float2half(b)) << 16);
}
__device__ __forceinline__ float2 unpack_h2(unsigned u) {
    return make_float2(__half2float(__ushort_as_half((unsigned short)(u & 0xffffu))),
                       __half2float(__ushort_as_half((unsigned short)(u >> 16))));
}

// ---------- 0: init bucket cursors ----------
__global__ void k_init(int* __restrict__ bcur) {
    int i = threadIdx.x + blockIdx.x * 1024;
    if (i < NBKT) bcur[i * 16] = i * BCAP;
}

// ---------- 1: fused hist+reserve+LDS-sort+coalesced scatter ----------
__global__ __launch_bounds__(1024) void k_scat(
    const int* __restrict__ row, const int* __restrict__ col,
    const float* __restrict__ w, int* __restrict__ bcur,
    int* __restrict__ irA, unsigned char* __restrict__ irB, int E)
{
    __shared__ int           sRW[CHUNK];     // 16 KB  sorted records
    __shared__ int           sDst[CHUNK];    // 16 KB  global destinations
    __shared__ unsigned char sCL[CHUNK];     // 4 KB   sorted col-low bytes
    __shared__ int hist[NBKT];               // hist -> lbase
    __shared__ int lcur[NBKT];
    __shared__ int sbase[NBKT];
    __shared__ int sc[1024];

    const int tid = threadIdx.x;
    for (int i = tid; i < NBKT; i += 1024) { hist[i] = 0; lcur[i] = 0; }
    __syncthreads();

    const int t0 = blockIdx.x * CHUNK;
    const int kend = min(CHUNK, E - t0);

    int rRW[EPT], rBC[EPT], nr = 0;
    for (int k = tid; k < kend; k += 1024) {
        int e = t0 + k;
        int c = col[e];
        int wq = min((int)(w[e] * 16384.0f + 0.5f), 16383);
        rRW[nr] = (row[e] << 14) | wq;
        rBC[nr] = c;
        atomicAdd(&hist[c >> 8], 1);
        ++nr;
    }
    __syncthreads();

    // reserve global ranges (device atomic, 586 padded cursors) and
    // local exclusive scan of the 586 bins (1024-wide Hillis-Steele)
    if (tid < NBKT) {
        int c = hist[tid];
        sbase[tid] = c ? atomicAdd(&bcur[tid * 16], c) : 0;   // absolute pos
    }
    int v = (tid < NBKT) ? hist[tid] : 0;
    sc[tid] = v; __syncthreads();
    for (int d = 1; d < 1024; d <<= 1) {
        int u = (tid >= d) ? sc[tid - d] : 0;
        __syncthreads();
        sc[tid] += u; __syncthreads();
    }
    if (tid < NBKT) hist[tid] = sc[tid] - v;       // lbase
    __syncthreads();

    // scatter into bucket-sorted LDS; precompute global destination
    for (int q = 0; q < nr; ++q) {
        int c = rBC[q];
        int b = c >> 8;
        int rank = atomicAdd(&lcur[b], 1);
        int p = hist[b] + rank;
        sRW[p] = rRW[q];
        sCL[p] = (unsigned char)(c & 255);
        int gp = sbase[b] + rank;                  // absolute (base b*BCAP)
        sDst[p] = (gp < (b + 1) * BCAP) ? gp : -1; // guard (never trips)
    }
    __syncthreads();

    // write-out: consecutive threads -> consecutive sorted positions -> runs
    for (int p = tid; p < kend; p += 1024) {
        int d = sDst[p];
        if (d >= 0) { irA[d] = sRW[p]; irB[d] = sCL[p]; }
    }
}

// ---------- 2: in-bucket sort by node; csr4, meta, fp16 xd ------
__global__ __launch_bounds__(1024) void k_sortbucket(
    const int* __restrict__ irA, const unsigned char* __restrict__ irB,
    int* __restrict__ csr4, const int* __restrict__ bcur,
    const float* __restrict__ x, int4* __restrict__ meta,
    unsigned* __restrict__ xdh, int N)
{
    __shared__ int           srw[BCAP];      // 19456 B
    __shared__ unsigned char scb[BCAP];      // 4864 B
    __shared__ int   hist[256];
    __shared__ float wsum[256];
    __shared__ int   nbase[256];
    __shared__ int   scur[256];

    const int b    = blockIdx.x;
    const int tid  = threadIdx.x;
    const int base = b * BCAP;
    const int c_n  = min(bcur[b * 16] - base, BCAP);

    if (tid < 256) { hist[tid] = 0; wsum[tid] = 0.0f; scur[tid] = 0; }
    __syncthreads();

    for (int k = tid; k < c_n; k += 1024) {
        int rw = irA[base + k];
        unsigned char c = irB[base + k];
        srw[k] = rw;
        scb[k] = c;
        atomicAdd(&hist[c], 1);
        atomicAdd(&wsum[c], (float)(rw & 16383) * (1.0f / 16384.0f));
    }
    __syncthreads();

    // 256-bin scan on the first 256 lanes (barriers reached by all threads)
    int v = 0;
    if (tid < 256) { v = hist[tid]; nbase[tid] = v; }
    __syncthreads();
    for (int d = 1; d < 256; d <<= 1) {
        int u = (tid >= d && tid < 256) ? nbase[tid - d] : 0;
        __syncthreads();
        if (tid < 256) nbase[tid] += u;
        __syncthreads();
    }
    if (tid < 256) {
        int excl = nbase[tid] - v;
        __syncthreads();
        nbase[tid] = excl;
    } else {
        __syncthreads();
    }

    if (tid < 256) {
        int node = b * 256 + tid;
        if (node < N) {
            float dv = rsqrtf(1.0f + wsum[tid]);
            meta[node] = make_int4(base + nbase[tid], v, __float_as_int(dv), 0);
            float xv[F_IN];
            #pragma unroll
            for (int j = 0; j < F_IN; ++j) xv[j] = dv * x[(size_t)node * F_IN + j];
            size_t o = (size_t)node * 6;
            xdh[o + 0] = pack_h2(xv[0], xv[1]);
            xdh[o + 1] = pack_h2(xv[2], xv[3]);
            xdh[o + 2] = pack_h2(xv[4], xv[5]);
            xdh[o + 3] = pack_h2(xv[6], xv[7]);
            xdh[o + 4] = pack_h2(xv[8], 0.0f);
            xdh[o + 5] = 0u;
        }
    }
    __syncthreads();

    for (int k = tid; k < c_n; k += 1024) {
        int rw = srw[k];
        unsigned char c = scb[k];
        int r = atomicAdd(&scur[c], 1);
        csr4[base + nbase[c] + r] = rw;      // (row<<14)|wq, grouped by node
    }
}

// -------- 3: gather layer 1 + fused MLP (4 lanes/node, fp16 tables) --------
__global__ __launch_bounds__(256) void k_g1mlp(
    const int* __restrict__ csr4, const int4* __restrict__ meta,
    const unsigned* __restrict__ xdh,
    const float* __restrict__ W1, const float* __restrict__ b1,
    const float* __restrict__ W2, unsigned* __restrict__ h2dh, int N)
{
    __shared__ float sW1[F_IN * F_HID];
    __shared__ float sb1[F_HID];
    __shared__ float sW2[F_HID * F_OUT];
    for (int t = threadIdx.x; t < F_IN * F_HID; t += 256) sW1[t] = W1[t];
    for (int t = threadIdx.x; t < F_HID;        t += 256) sb1[t] = b1[t];
    for (int t = threadIdx.x; t < F_HID * F_OUT; t += 256) sW2[t] = W2[t];
    __syncthreads();

    int t   = blockIdx.x * 256 + threadIdx.x;
    int i   = t >> 2;
    int sub = t & 3;
    if (i >= N) return;
    int4 m = meta[i];
    float dv = __int_as_float(m.z);

    float acc[F_IN];
    #pragma unroll
    for (int j = 0; j < F_IN; ++j) acc[j] = 0.0f;
    if (sub == 0) {
        size_t o = (size_t)i * 6;
        uint2 u01 = *reinterpret_cast<const uint2*>(xdh + o);
        uint2 u23 = *reinterpret_cast<const uint2*>(xdh + o + 2);
        unsigned u4 = xdh[o + 4];
        float2 f0 = unpack_h2(u01.x), f1 = unpack_h2(u01.y),
               f2 = unpack_h2(u23.x), f3 = unpack_h2(u23.y),
               f4 = unpack_h2(u4);
        acc[0] = f0.x; acc[1] = f0.y; acc[2] = f1.x; acc[3] = f1.y;
        acc[4] = f2.x; acc[5] = f2.y; acc[6] = f3.x; acc[7] = f3.y;
        acc[8] = f4.x;
    }
    int s = m.x, tend = m.x + m.y;
    for (int e = s + sub; e < tend; e += 4) {
        int v = nt_load_int(&csr4[e]);
        int r = (int)((unsigned)v >> 14);
        float wv = (float)(v & 16383) * (1.0f / 16384.0f);
        size_t o = (size_t)r * 6;
        uint2 u01 = *reinterpret_cast<const uint2*>(xdh + o);
        uint2 u23 = *reinterpret_cast<const uint2*>(xdh + o + 2);
        unsigned u4 = xdh[o + 4];
        float2 f0 = unpack_h2(u01.x), f1 = unpack_h2(u01.y),
               f2 = unpack_h2(u23.x), f3 = unpack_h2(u23.y),
               f4 = unpack_h2(u4);
        acc[0] = fmaf(wv, f0.x, acc[0]); acc[1] = fmaf(wv, f0.y, acc[1]);
        acc[2] = fmaf(wv, f1.x, acc[2]); acc[3] = fmaf(wv, f1.y, acc[3]);
        acc[4] = fmaf(wv, f2.x, acc[4]); acc[5] = fmaf(wv, f2.y, acc[5]);
        acc[6] = fmaf(wv, f3.x, acc[6]); acc[7] = fmaf(wv, f3.y, acc[7]);
        acc[8] = fmaf(wv, f4.x, acc[8]);
    }
    #pragma unroll
    for (int d = 1; d < 4; d <<= 1) {
        #pragma unroll
        for (int j = 0; j < F_IN; ++j)
            acc[j] += __shfl_xor(acc[j], d, 4);
    }
    #pragma unroll
    for (int j = 0; j < F_IN; ++j) acc[j] *= dv;

    float o7[F_OUT];
    #pragma unroll
    for (int c = 0; c < F_OUT; ++c) o7[c] = 0.0f;
    int ks = sub * 8;
    #pragma unroll
    for (int k = 0; k < 8; ++k) {
        float hk = sb1[ks + k];
        #pragma unroll
        for (int j = 0; j < F_IN; ++j) hk = fmaf(acc[j], sW1[j * F_HID + ks + k], hk);
        hk = fmaxf(hk, 0.0f);
        #pragma unroll
        for (int c = 0; c < F_OUT; ++c) o7[c] = fmaf(hk, sW2[(ks + k) * F_OUT + c], o7[c]);
    }
    #pragma unroll
    for (int d = 1; d < 4; d <<= 1) {
        #pragma unroll
        for (int c = 0; c < F_OUT; ++c)
            o7[c] += __shfl_xor(o7[c], d, 4);
    }
    float pa = dv * o7[2 * sub];
    float pb = (2 * sub + 1 < F_OUT) ? dv * o7[2 * sub + 1] : 0.0f;
    h2dh[(size_t)i * 4 + sub] = pack_h2(pa, pb);
}

// -------- 4: gather layer 2 + bias + log_softmax (4 lanes/node) --------
__global__ __launch_bounds__(256) void k_g2ls(
    const int* __restrict__ csr4, const int4* __restrict__ meta,
    const unsigned* __restrict__ h2dh, const float* __restrict__ b2,
    float* __restrict__ out, int N)
{
    int t   = blockIdx.x * 256 + threadIdx.x;
    int i   = t >> 2;
    int sub = t & 3;
    if (i >= N) return;
    int4 m = meta[i];
    float dv = __int_as_float(m.z);

    float acc[F_OUT];
    #pragma unroll
    for (int c = 0; c < F_OUT; ++c) acc[c] = 0.0f;
    if (sub == 0) {
        uint4 h4 = *reinterpret_cast<const uint4*>(h2dh + (size_t)i * 4);
        float2 f0 = unpack_h2(h4.x), f1 = unpack_h2(h4.y),
               f2 = unpack_h2(h4.z), f3 = unpack_h2(h4.w);
        acc[0] = f0.x; acc[1] = f0.y; acc[2] = f1.x; acc[3] = f1.y;
        acc[4] = f2.x; acc[5] = f2.y; acc[6] = f3.x;
    }
    int s = m.x, tend = m.x + m.y;
    for (int e = s + sub; e < tend; e += 4) {
        int v = nt_load_int(&csr4[e]);
        int r = (int)((unsigned)v >> 14);
        float wv = (float)(v & 16383) * (1.0f / 16384.0f);
        uint4 h4 = *reinterpret_cast<const uint4*>(h2dh + (size_t)r * 4);
        float2 f0 = unpack_h2(h4.x), f1 = unpack_h2(h4.y),
               f2 = unpack_h2(h4.z), f3 = unpack_h2(h4.w);
        acc[0] = fmaf(wv, f0.x, acc[0]); acc[1] = fmaf(wv, f0.y, acc[1]);
        acc[2] = fmaf(wv, f1.x, acc[2]); acc[3] = fmaf(wv, f1.y, acc[3]);
        acc[4] = fmaf(wv, f2.x, acc[4]); acc[5] = fmaf(wv, f2.y, acc[5]);
        acc[6] = fmaf(wv, f3.x, acc[6]);
    }
    #pragma unroll
    for (int d = 1; d < 4; d <<= 1) {
        #pragma unroll
        for (int c = 0; c < F_OUT; ++c)
            acc[c] += __shfl_xor(acc[c], d, 4);
    }

    float vv[F_OUT];
    float mx = -1e30f;
    #pragma unroll
    for (int c = 0; c < F_OUT; ++c) {
        vv[c] = dv * acc[c] + b2[c];
        mx = fmaxf(mx, vv[c]);
    }
    float ss = 0.0f;
    #pragma unroll
    for (int c = 0; c < F_OUT; ++c) ss += __expf(vv[c] - mx);
    float ls = __logf(ss);
    for (int c = sub; c < F_OUT; c += 4)
        out[(size_t)i * F_OUT + c] = vv[c] - mx - ls;
}

extern "C" void kernel_launch(void* const* d_in, const int* in_sizes, int n_in,
                              void* d_out, int out_size, void* d_ws, size_t ws_size,
                              hipStream_t stream) {
    const float* x  = (const float*)d_in[0];
    const int*   ei = (const int*)  d_in[1];   // [2, E]: row ptr then col ptr
    const float* ew = (const float*)d_in[2];
    const float* W1 = (const float*)d_in[3];
    const float* b1 = (const float*)d_in[4];
    const float* W2 = (const float*)d_in[5];
    const float* b2 = (const float*)d_in[6];
    float* out = (float*)d_out;

    const int N = in_sizes[0] / F_IN;
    const int E = in_sizes[2];
    const int* row = ei;
    const int* col = ei + E;
    const int nchunk = (E + CHUNK - 1) / CHUNK;

    // workspace (~34 MB, no overlays):
    char* p = (char*)d_ws;
    int4*     meta  = (int4*)p;      p += sizeof(int4) * (size_t)N;             // 2.4MB (16B aligned first)
    int*      irA   = (int*)p;       p += sizeof(int)  * (size_t)NBKT * BCAP;   // 11.4MB
    int*      csr4  = (int*)p;       p += sizeof(int)  * (size_t)NBKT * BCAP;   // 11.4MB
    unsigned* xdh   = (unsigned*)p;  p += sizeof(unsigned) * (size_t)N * 6;     // 3.6MB
    unsigned* h2dh  = (unsigned*)p;  p += sizeof(unsigned) * (size_t)N * 4;     // 2.4MB
    int*      bcur  = (int*)p;       p += sizeof(int) * (size_t)NBKT * 16;      // 37KB
    unsigned char* irB = (unsigned char*)p;                                     // 2.85MB

    const int gN4 = (4 * N + 255) / 256;

    k_init      <<<1, 1024, 0, stream>>>(bcur);
    k_scat      <<<nchunk, 1024, 0, stream>>>(row, col, ew, bcur, irA, irB, E);
    k_sortbucket<<<NBKT, 1024, 0, stream>>>(irA, irB, csr4, bcur, x, meta, xdh, N);
    k_g1mlp     <<<gN4, 256, 0, stream>>>(csr4, meta, xdh, W1, b1, W2, h2dh, N);
    k_g2ls      <<<gN4, 256, 0, stream>>>(csr4, meta, h2dh, b2, out, N);
}

// Round 19
// 130.797 us; speedup vs baseline: 1.0439x; 1.0439x over previous
//
#include <hip/hip_runtime.h>
#include <hip/hip_fp16.h>

constexpr int F_IN  = 9;
constexpr int F_HID = 32;
constexpr int F_OUT = 7;

constexpr int NBKT   = 586;      // ceil(150000/256) buckets of 256 nodes
constexpr int BCAP   = 4864;     // mean 4096 + 12 sigma
constexpr int CHUNK  = 4096;     // edges per scat block
constexpr int SCT    = 512;      // k_scat threads  (3 blocks/CU -> 768 >= 586: ONE round)
constexpr int EPT    = CHUNK / SCT;    // 8 edges per thread

__device__ __forceinline__ int nt_load_int(const int* p) {
    return __builtin_nontemporal_load(p);
}
__device__ __forceinline__ unsigned pack_h2(float a, float b) {
    return (unsigned)__half_as_ushort(__float2half(a)) |
           ((unsigned)__half_as_ushort(__float2half(b)) << 16);
}
__device__ __forceinline__ float2 unpack_h2(unsigned u) {
    return make_float2(__half2float(__ushort_as_half((unsigned short)(u & 0xffffu))),
                       __half2float(__ushort_as_half((unsigned short)(u >> 16))));
}

// ---------- 0: init bucket cursors ----------
__global__ void k_init(int* __restrict__ bcur) {
    int i = threadIdx.x + blockIdx.x * 1024;
    if (i < NBKT) bcur[i * 16] = i * BCAP;
}

// ---------- 1: fused hist+reserve+LDS-sort+coalesced scatter (512 thr) ----------
__global__ __launch_bounds__(SCT) void k_scat(
    const int* __restrict__ row, const int* __restrict__ col,
    const float* __restrict__ w, int* __restrict__ bcur,
    int* __restrict__ irA, unsigned char* __restrict__ irB, int E)
{
    __shared__ int           sRW[CHUNK];     // 16 KB  sorted records
    __shared__ int           sDst[CHUNK];    // 16 KB  global destinations
    __shared__ unsigned char sCL[CHUNK];     // 4 KB   sorted col-low bytes
    __shared__ int hist[NBKT];               // counts -> lbase
    __shared__ int lcur[NBKT];
    __shared__ int sbase[NBKT];
    __shared__ int sc[SCT];

    const int tid = threadIdx.x;
    for (int i = tid; i < NBKT; i += SCT) { hist[i] = 0; lcur[i] = 0; }
    __syncthreads();

    const int t0 = blockIdx.x * CHUNK;
    const int kend = min(CHUNK, E - t0);

    int rRW[EPT], rBC[EPT], nr = 0;
    for (int k = tid; k < kend; k += SCT) {
        int e = t0 + k;
        int c = col[e];
        int wq = min((int)(w[e] * 16384.0f + 0.5f), 16383);
        rRW[nr] = (row[e] << 14) | wq;
        rBC[nr] = c;
        atomicAdd(&hist[c >> 8], 1);
        ++nr;
    }
    __syncthreads();

    // global range reservation (586 padded cursors) + LDS-slot assignment.
    // Thread t owns bins {t, t+512}; LDS slot order is arbitrary-but-fixed.
    int a = (tid < NBKT) ? hist[tid] : 0;
    int b = (tid + SCT < NBKT) ? hist[tid + SCT] : 0;
    for (int i = tid; i < NBKT; i += SCT) {
        int c = hist[i];
        sbase[i] = c ? atomicAdd(&bcur[i * 16], c) : 0;   // absolute pos
    }
    int v = a + b;
    sc[tid] = v; __syncthreads();
    for (int d = 1; d < SCT; d <<= 1) {
        int u = (tid >= d) ? sc[tid - d] : 0;
        __syncthreads();
        sc[tid] += u; __syncthreads();
    }
    int excl = sc[tid] - v;
    if (tid < NBKT) hist[tid] = excl;                 // lbase(bin t)
    if (tid + SCT < NBKT) hist[tid + SCT] = excl + a; // lbase(bin t+512)
    __syncthreads();

    // scatter into bucket-sorted LDS; precompute global destination
    #pragma unroll
    for (int q = 0; q < EPT; ++q) {
        if (q >= nr) break;
        int c = rBC[q];
        int bb = c >> 8;
        int rank = atomicAdd(&lcur[bb], 1);
        int p = hist[bb] + rank;
        sRW[p] = rRW[q];
        sCL[p] = (unsigned char)(c & 255);
        int gp = sbase[bb] + rank;                     // absolute position
        sDst[p] = (gp < (bb + 1) * BCAP) ? gp : -1;    // guard (never trips)
    }
    __syncthreads();

    // write-out: consecutive threads -> consecutive sorted positions -> runs
    for (int p = tid; p < kend; p += SCT) {
        int d = sDst[p];
        if (d >= 0) { irA[d] = sRW[p]; irB[d] = sCL[p]; }
    }
}

// ---------- 2: in-bucket sort by node; csr4, meta, fp16 xd (512 thr) ------
__global__ __launch_bounds__(512) void k_sortbucket(
    const int* __restrict__ irA, const unsigned char* __restrict__ irB,
    int* __restrict__ csr4, const int* __restrict__ bcur,
    const float* __restrict__ x, int4* __restrict__ meta,
    unsigned* __restrict__ xdh, int N)
{
    __shared__ int           srw[BCAP];      // 19456 B
    __shared__ unsigned char scb[BCAP];      // 4864 B
    __shared__ int   hist[256];
    __shared__ float wsum[256];
    __shared__ int   nbase[256];
    __shared__ int   scur[256];

    const int b    = blockIdx.x;
    const int tid  = threadIdx.x;
    const int base = b * BCAP;
    const int c_n  = min(bcur[b * 16] - base, BCAP);

    if (tid < 256) { hist[tid] = 0; wsum[tid] = 0.0f; scur[tid] = 0; }
    __syncthreads();

    for (int k = tid; k < c_n; k += 512) {
        int rw = irA[base + k];
        unsigned char c = irB[base + k];
        srw[k] = rw;
        scb[k] = c;
        atomicAdd(&hist[c], 1);
        atomicAdd(&wsum[c], (float)(rw & 16383) * (1.0f / 16384.0f));
    }
    __syncthreads();

    // 256-bin scan on the first 256 lanes (barriers reached by all threads)
    int v = 0;
    if (tid < 256) { v = hist[tid]; nbase[tid] = v; }
    __syncthreads();
    for (int d = 1; d < 256; d <<= 1) {
        int u = (tid >= d && tid < 256) ? nbase[tid - d] : 0;
        __syncthreads();
        if (tid < 256) nbase[tid] += u;
        __syncthreads();
    }
    if (tid < 256) {
        int excl = nbase[tid] - v;
        __syncthreads();
        nbase[tid] = excl;
    } else {
        __syncthreads();
    }

    if (tid < 256) {
        int node = b * 256 + tid;
        if (node < N) {
            float dv = rsqrtf(1.0f + wsum[tid]);
            meta[node] = make_int4(base + nbase[tid], v, __float_as_int(dv), 0);
            float xv[F_IN];
            #pragma unroll
            for (int j = 0; j < F_IN; ++j) xv[j] = dv * x[(size_t)node * F_IN + j];
            size_t o = (size_t)node * 6;
            xdh[o + 0] = pack_h2(xv[0], xv[1]);
            xdh[o + 1] = pack_h2(xv[2], xv[3]);
            xdh[o + 2] = pack_h2(xv[4], xv[5]);
            xdh[o + 3] = pack_h2(xv[6], xv[7]);
            xdh[o + 4] = pack_h2(xv[8], 0.0f);
            xdh[o + 5] = 0u;
        }
    }
    __syncthreads();

    for (int k = tid; k < c_n; k += 512) {
        int rw = srw[k];
        unsigned char c = scb[k];
        int r = atomicAdd(&scur[c], 1);
        csr4[base + nbase[c] + r] = rw;      // (row<<14)|wq, grouped by node
    }
}

// -------- 3: gather layer 1 + fused MLP (4 lanes/node, fp16 tables) --------
__global__ __launch_bounds__(256) void k_g1mlp(
    const int* __restrict__ csr4, const int4* __restrict__ meta,
    const unsigned* __restrict__ xdh,
    const float* __restrict__ W1, const float* __restrict__ b1,
    const float* __restrict__ W2, unsigned* __restrict__ h2dh, int N)
{
    __shared__ float sW1[F_IN * F_HID];
    __shared__ float sb1[F_HID];
    __shared__ float sW2[F_HID * F_OUT];
    for (int t = threadIdx.x; t < F_IN * F_HID; t += 256) sW1[t] = W1[t];
    for (int t = threadIdx.x; t < F_HID;        t += 256) sb1[t] = b1[t];
    for (int t = threadIdx.x; t < F_HID * F_OUT; t += 256) sW2[t] = W2[t];
    __syncthreads();

    int t   = blockIdx.x * 256 + threadIdx.x;
    int i   = t >> 2;
    int sub = t & 3;
    if (i >= N) return;
    int4 m = meta[i];
    float dv = __int_as_float(m.z);

    float acc[F_IN];
    #pragma unroll
    for (int j = 0; j < F_IN; ++j) acc[j] = 0.0f;
    if (sub == 0) {
        size_t o = (size_t)i * 6;
        uint2 u01 = *reinterpret_cast<const uint2*>(xdh + o);
        uint2 u23 = *reinterpret_cast<const uint2*>(xdh + o + 2);
        unsigned u4 = xdh[o + 4];
        float2 f0 = unpack_h2(u01.x), f1 = unpack_h2(u01.y),
               f2 = unpack_h2(u23.x), f3 = unpack_h2(u23.y),
               f4 = unpack_h2(u4);
        acc[0] = f0.x; acc[1] = f0.y; acc[2] = f1.x; acc[3] = f1.y;
        acc[4] = f2.x; acc[5] = f2.y; acc[6] = f3.x; acc[7] = f3.y;
        acc[8] = f4.x;
    }
    int s = m.x, tend = m.x + m.y;
    for (int e = s + sub; e < tend; e += 4) {
        int v = nt_load_int(&csr4[e]);
        int r = (int)((unsigned)v >> 14);
        float wv = (float)(v & 16383) * (1.0f / 16384.0f);
        size_t o = (size_t)r * 6;
        uint2 u01 = *reinterpret_cast<const uint2*>(xdh + o);
        uint2 u23 = *reinterpret_cast<const uint2*>(xdh + o + 2);
        unsigned u4 = xdh[o + 4];
        float2 f0 = unpack_h2(u01.x), f1 = unpack_h2(u01.y),
               f2 = unpack_h2(u23.x), f3 = unpack_h2(u23.y),
               f4 = unpack_h2(u4);
        acc[0] = fmaf(wv, f0.x, acc[0]); acc[1] = fmaf(wv, f0.y, acc[1]);
        acc[2] = fmaf(wv, f1.x, acc[2]); acc[3] = fmaf(wv, f1.y, acc[3]);
        acc[4] = fmaf(wv, f2.x, acc[4]); acc[5] = fmaf(wv, f2.y, acc[5]);
        acc[6] = fmaf(wv, f3.x, acc[6]); acc[7] = fmaf(wv, f3.y, acc[7]);
        acc[8] = fmaf(wv, f4.x, acc[8]);
    }
    #pragma unroll
    for (int d = 1; d < 4; d <<= 1) {
        #pragma unroll
        for (int j = 0; j < F_IN; ++j)
            acc[j] += __shfl_xor(acc[j], d, 4);
    }
    #pragma unroll
    for (int j = 0; j < F_IN; ++j) acc[j] *= dv;

    float o7[F_OUT];
    #pragma unroll
    for (int c = 0; c < F_OUT; ++c) o7[c] = 0.0f;
    int ks = sub * 8;
    #pragma unroll
    for (int k = 0; k < 8; ++k) {
        float hk = sb1[ks + k];
        #pragma unroll
        for (int j = 0; j < F_IN; ++j) hk = fmaf(acc[j], sW1[j * F_HID + ks + k], hk);
        hk = fmaxf(hk, 0.0f);
        #pragma unroll
        for (int c = 0; c < F_OUT; ++c) o7[c] = fmaf(hk, sW2[(ks + k) * F_OUT + c], o7[c]);
    }
    #pragma unroll
    for (int d = 1; d < 4; d <<= 1) {
        #pragma unroll
        for (int c = 0; c < F_OUT; ++c)
            o7[c] += __shfl_xor(o7[c], d, 4);
    }
    float pa = dv * o7[2 * sub];
    float pb = (2 * sub + 1 < F_OUT) ? dv * o7[2 * sub + 1] : 0.0f;
    h2dh[(size_t)i * 4 + sub] = pack_h2(pa, pb);
}

// -------- 4: gather layer 2 + bias + log_softmax (4 lanes/node) --------
__global__ __launch_bounds__(256) void k_g2ls(
    const int* __restrict__ csr4, const int4* __restrict__ meta,
    const unsigned* __restrict__ h2dh, const float* __restrict__ b2,
    float* __restrict__ out, int N)
{
    int t   = blockIdx.x * 256 + threadIdx.x;
    int i   = t >> 2;
    int sub = t & 3;
    if (i >= N) return;
    int4 m = meta[i];
    float dv = __int_as_float(m.z);

    float acc[F_OUT];
    #pragma unroll
    for (int c = 0; c < F_OUT; ++c) acc[c] = 0.0f;
    if (sub == 0) {
        uint4 h4 = *reinterpret_cast<const uint4*>(h2dh + (size_t)i * 4);
        float2 f0 = unpack_h2(h4.x), f1 = unpack_h2(h4.y),
               f2 = unpack_h2(h4.z), f3 = unpack_h2(h4.w);
        acc[0] = f0.x; acc[1] = f0.y; acc[2] = f1.x; acc[3] = f1.y;
        acc[4] = f2.x; acc[5] = f2.y; acc[6] = f3.x;
    }
    int s = m.x, tend = m.x + m.y;
    for (int e = s + sub; e < tend; e += 4) {
        int v = nt_load_int(&csr4[e]);
        int r = (int)((unsigned)v >> 14);
        float wv = (float)(v & 16383) * (1.0f / 16384.0f);
        uint4 h4 = *reinterpret_cast<const uint4*>(h2dh + (size_t)r * 4);
        float2 f0 = unpack_h2(h4.x), f1 = unpack_h2(h4.y),
               f2 = unpack_h2(h4.z), f3 = unpack_h2(h4.w);
        acc[0] = fmaf(wv, f0.x, acc[0]); acc[1] = fmaf(wv, f0.y, acc[1]);
        acc[2] = fmaf(wv, f1.x, acc[2]); acc[3] = fmaf(wv, f1.y, acc[3]);
        acc[4] = fmaf(wv, f2.x, acc[4]); acc[5] = fmaf(wv, f2.y, acc[5]);
        acc[6] = fmaf(wv, f3.x, acc[6]);
    }
    #pragma unroll
    for (int d = 1; d < 4; d <<= 1) {
        #pragma unroll
        for (int c = 0; c < F_OUT; ++c)
            acc[c] += __shfl_xor(acc[c], d, 4);
    }

    float vv[F_OUT];
    float mx = -1e30f;
    #pragma unroll
    for (int c = 0; c < F_OUT; ++c) {
        vv[c] = dv * acc[c] + b2[c];
        mx = fmaxf(mx, vv[c]);
    }
    float ss = 0.0f;
    #pragma unroll
    for (int c = 0; c < F_OUT; ++c) ss += __expf(vv[c] - mx);
    float ls = __logf(ss);
    for (int c = sub; c < F_OUT; c += 4)
        out[(size_t)i * F_OUT + c] = vv[c] - mx - ls;
}

extern "C" void kernel_launch(void* const* d_in, const int* in_sizes, int n_in,
                              void* d_out, int out_size, void* d_ws, size_t ws_size,
                              hipStream_t stream) {
    const float* x  = (const float*)d_in[0];
    const int*   ei = (const int*)  d_in[1];   // [2, E]: row ptr then col ptr
    const float* ew = (const float*)d_in[2];
    const float* W1 = (const float*)d_in[3];
    const float* b1 = (const float*)d_in[4];
    const float* W2 = (const float*)d_in[5];
    const float* b2 = (const float*)d_in[6];
    float* out = (float*)d_out;

    const int N = in_sizes[0] / F_IN;
    const int E = in_sizes[2];
    const int* row = ei;
    const int* col = ei + E;
    const int nchunk = (E + CHUNK - 1) / CHUNK;

    // workspace (~34 MB, no overlays):
    char* p = (char*)d_ws;
    int4*     meta  = (int4*)p;      p += sizeof(int4) * (size_t)N;             // 2.4MB
    int*      irA   = (int*)p;       p += sizeof(int)  * (size_t)NBKT * BCAP;   // 11.4MB
    int*      csr4  = (int*)p;       p += sizeof(int)  * (size_t)NBKT * BCAP;   // 11.4MB
    unsigned* xdh   = (unsigned*)p;  p += sizeof(unsigned) * (size_t)N * 6;     // 3.6MB
    unsigned* h2dh  = (unsigned*)p;  p += sizeof(unsigned) * (size_t)N * 4;     // 2.4MB
    int*      bcur  = (int*)p;       p += sizeof(int) * (size_t)NBKT * 16;      // 37KB
    unsigned char* irB = (unsigned char*)p;                                     // 2.85MB

    const int gN4 = (4 * N + 255) / 256;

    k_init      <<<1, 1024, 0, stream>>>(bcur);
    k_scat      <<<nchunk, SCT, 0, stream>>>(row, col, ew, bcur, irA, irB, E);
    k_sortbucket<<<NBKT, 512, 0, stream>>>(irA, irB, csr4, bcur, x, meta, xdh, N);
    k_g1mlp     <<<gN4, 256, 0, stream>>>(csr4, meta, xdh, W1, b1, W2, h2dh, N);
    k_g2ls      <<<gN4, 256, 0, stream>>>(csr4, meta, h2dh, b2, out, N);
}